// Round 4
// baseline (1048.827 us; speedup 1.0000x reference)
//
#include <hip/hip_runtime.h>
#include <hip/hip_bf16.h>
#include <math.h>

#define T_TOKENS 8192
#define DDIM 1024
#define HDIM 4096
#define NEXP 8
#define CAP 8192      // max tokens per expert
#define MAXTILES 136  // sum_e ceil(cnt_e/128) <= 128 + 7; 136 % 8 == 0 (XCD math)

typedef __bf16 bf16;
typedef __bf16 bf16x4 __attribute__((ext_vector_type(4)));
typedef __bf16 bf16x8 __attribute__((ext_vector_type(8)));
typedef float  floatx16 __attribute__((ext_vector_type(16)));

// async global->LDS, 16 bytes per lane; LDS dest = wave-uniform base + lane*16.
__device__ static inline void async_load16(const void* g, void* l)
{
    __builtin_amdgcn_global_load_lds(
        (const __attribute__((address_space(1))) void*)g,
        (__attribute__((address_space(3))) void*)l, 16, 0, 0);
}

// ---------------------------------------------------------------------------
// Kernel 1: router. 4 waves/block, one token per wave. fp32 logits (exact;
// selection matches jax.lax.top_k incl. lowest-index tie-break).
// ---------------------------------------------------------------------------
__global__ void router_kernel(const float* __restrict__ x,
                              const float* __restrict__ gw,
                              const float* __restrict__ gbias,
                              float* __restrict__ logits_out,
                              int* counts, int* token_of, float* wtab,
                              int* selpack)
{
    int t = blockIdx.x * 4 + (threadIdx.x >> 6);
    int l = threadIdx.x & 63;
    const float4* xr = (const float4*)(x + (size_t)t * DDIM);

    float p[NEXP];
#pragma unroll
    for (int e = 0; e < NEXP; ++e) p[e] = 0.f;

#pragma unroll
    for (int it = 0; it < 4; ++it) {
        int d4 = it * 64 + l;
        float4 v = xr[d4];
        float vv[4] = {v.x, v.y, v.z, v.w};
#pragma unroll
        for (int j = 0; j < 4; ++j) {
            const float4* g4 = (const float4*)(gw + (size_t)(d4 * 4 + j) * NEXP);
            float4 ga = g4[0], gb4 = g4[1];
            p[0] += vv[j] * ga.x;  p[1] += vv[j] * ga.y;
            p[2] += vv[j] * ga.z;  p[3] += vv[j] * ga.w;
            p[4] += vv[j] * gb4.x; p[5] += vv[j] * gb4.y;
            p[6] += vv[j] * gb4.z; p[7] += vv[j] * gb4.w;
        }
    }
#pragma unroll
    for (int e = 0; e < NEXP; ++e) {
#pragma unroll
        for (int off = 32; off; off >>= 1) p[e] += __shfl_xor(p[e], off);
        p[e] += gbias[e];
    }
    if (l < NEXP) logits_out[(size_t)t * NEXP + l] = p[l];

    if (l == 0) {
        int e0 = 0;
#pragma unroll
        for (int e = 1; e < NEXP; ++e) if (p[e] > p[e0]) e0 = e;
        int e1 = -1;
#pragma unroll
        for (int e = 0; e < NEXP; ++e) {
            if (e == e0) continue;
            if (e1 < 0 || p[e] > p[e1]) e1 = e;
        }
        float w0 = 1.f / (1.f + expf(p[e1] - p[e0]));
        float w1 = 1.f / (1.f + expf(p[e0] - p[e1]));
        int s0 = atomicAdd(&counts[e0], 1);
        int s1 = atomicAdd(&counts[e1], 1);
        token_of[e0 * CAP + s0] = t;
        token_of[e1 * CAP + s1] = t;
        wtab[e0 * CAP + s0] = w0;
        wtab[e1 * CAP + s1] = w1;
        selpack[t] = e0 | (e1 << 8);   // kept for debug; unused downstream
    }
}

// ---------------------------------------------------------------------------
// Kernel 2: offsets + XCD-transposed 128-row tile list.
// tiles[p] for p = c + 8*k carries ordered-tile index c*per + k, so the
// contiguous (≈ one expert) run of tiles lands on one XCD (linear%8 == p%8,
// since grid.x == 136 ≡ 0 mod 8) -> per-XCD L2 holds ONE expert's B.
// ---------------------------------------------------------------------------
__global__ void offsets_kernel(const int* __restrict__ counts,
                               int* __restrict__ offsets,
                               int* __restrict__ tiles)
{
    if (threadIdx.x == 0) {
        int tmp[MAXTILES];
        int a = 0, nt = 0;
        for (int e = 0; e < NEXP; ++e) {
            offsets[e] = a;
            for (int r = 0; r < counts[e]; r += 128)
                tmp[nt++] = (e << 24) | (a + r);
            a += counts[e];
        }
        offsets[NEXP] = a;   // == 2*T_TOKENS
        int per = (nt + 7) >> 3;
        for (int p = 0; p < MAXTILES; ++p) {
            int c = p & 7, k = p >> 3;
            int src = c * per + k;
            tiles[p] = (k < per && src < nt) ? tmp[src] : -1;
        }
    }
}

// ---------------------------------------------------------------------------
// Kernel 3: gather over compact rows. 4 waves/block, one row per wave.
// ---------------------------------------------------------------------------
__global__ void gather_kernel(const float* __restrict__ x,
                              const int* __restrict__ offsets,
                              const int* __restrict__ token_of,
                              bf16* __restrict__ xg)
{
    int row = blockIdx.x * 4 + (threadIdx.x >> 6);
    int l = threadIdx.x & 63;
    int e = 0;
#pragma unroll
    for (int i = 1; i < NEXP; ++i) e += (row >= offsets[i]);
    int t = token_of[e * CAP + (row - offsets[e])];
    const float4* src = (const float4*)(x + (size_t)t * DDIM);
    bf16x4* dst = (bf16x4*)(xg + (size_t)row * DDIM);
#pragma unroll
    for (int it = 0; it < 4; ++it) {
        float4 v = src[it * 64 + l];
        bf16x4 b;
        b[0] = (bf16)v.x; b[1] = (bf16)v.y; b[2] = (bf16)v.z; b[3] = (bf16)v.w;
        dst[it * 64 + l] = b;
    }
}

// ---------------------------------------------------------------------------
// Kernel 4: per-expert transpose + fp32->bf16, 16 B/lane both directions.
// in [E][R][C] fp32 -> out [E][C][R] bf16.  64x64 tile, 256 threads.
// ---------------------------------------------------------------------------
__global__ void transpose_cvt_kernel(const float* __restrict__ in,
                                     bf16* __restrict__ out, int R, int C)
{
    __shared__ bf16 tile[64][68];
    int e = blockIdx.z;
    const float* src = in + (size_t)e * R * C;
    bf16* dst = out + (size_t)e * R * C;
    int r0 = blockIdx.y * 64, c0 = blockIdx.x * 64;
    int t = threadIdx.x;
    int lr = t >> 4, c4 = t & 15;
#pragma unroll
    for (int it = 0; it < 4; ++it) {
        int r = lr + it * 16;
        float4 v = *(const float4*)(src + (size_t)(r0 + r) * C + c0 + c4 * 4);
        bf16x4 b;
        b[0] = (bf16)v.x; b[1] = (bf16)v.y; b[2] = (bf16)v.z; b[3] = (bf16)v.w;
        *(bf16x4*)(&tile[r][c4 * 4]) = b;
    }
    __syncthreads();
    int oc = t >> 3, rseg = (t & 7) * 8;
#pragma unroll
    for (int it = 0; it < 2; ++it) {
        int c = oc + it * 32;
        bf16x8 v;
#pragma unroll
        for (int j = 0; j < 8; ++j) v[j] = tile[rseg + j][c];
        *(bf16x8*)(dst + (size_t)(c0 + c) * R + r0 + rseg) = v;
    }
}

// ---------------------------------------------------------------------------
// Stage 128x64 bf16 tile -> unpadded LDS via global_load_lds, XOR chunk
// swizzle on the global side (phys chunk p holds logical p ^ (row&7)).
// ---------------------------------------------------------------------------
template<int KTOT>
__device__ static inline void stage_tile(const bf16* __restrict__ gbase,
                                         bf16* lds, int wave, int lane, int valid)
{
#pragma unroll
    for (int it = 0; it < 4; ++it) {
        int rbase = wave * 32 + it * 8;          // wave-uniform
        int rloc  = rbase + (lane >> 3);
        int grow  = rloc < valid ? rloc : (valid - 1);
        int chunk = (lane & 7) ^ (rloc & 7);
        const bf16* g = gbase + (size_t)grow * KTOT + chunk * 8;
        async_load16(g, lds + rbase * 64);
    }
}

__device__ static inline float fast_gelu(float v)
{
    float z = v * (2.302236479f + 0.1029451170f * v * v);
    float ex = __builtin_amdgcn_exp2f(z);
    return v * ex * __builtin_amdgcn_rcpf(ex + 1.f);
}

// ---------------------------------------------------------------------------
// Core 128x128 K-loop, 32x32x16 MFMA: each wave 64x64 as 2x2 subtiles of
// 32x32, acc 4 x floatx16 (64 AGPRs). A/B frag: [m=lane&31][k=(lane>>5)*8+j].
// ---------------------------------------------------------------------------
#define GEMM_CORE(KTOT)                                                        \
    int tid = threadIdx.x;                                                     \
    int lane = tid & 63, wave = tid >> 6;                                      \
    int wr = wave >> 1, wc = wave & 1;                                         \
    int m32 = lane & 31, khalf = lane >> 5;                                    \
    int swz = m32 & 7;                                                         \
    floatx16 acc[2][2];                                                        \
    _Pragma("unroll") for (int i = 0; i < 2; ++i)                              \
    _Pragma("unroll") for (int j = 0; j < 2; ++j)                              \
    _Pragma("unroll") for (int r = 0; r < 16; ++r) acc[i][j][r] = 0.f;         \
    for (int k0 = 0; k0 < KTOT; k0 += 64) {                                    \
        stage_tile<KTOT>(A + k0, As, wave, lane, valid);                       \
        stage_tile<KTOT>(B + k0, Bs, wave, lane, 128);                         \
        __syncthreads();                                                       \
        _Pragma("unroll") for (int s = 0; s < 4; ++s) {                        \
            int pofs = (((2 * s + khalf) ^ swz) * 8);                          \
            bf16x8 af[2], bfr[2];                                              \
            _Pragma("unroll") for (int i = 0; i < 2; ++i)                      \
                af[i] = *(const bf16x8*)(&As[(wr * 64 + i * 32 + m32) * 64 + pofs]); \
            _Pragma("unroll") for (int j = 0; j < 2; ++j)                      \
                bfr[j] = *(const bf16x8*)(&Bs[(wc * 64 + j * 32 + m32) * 64 + pofs]); \
            _Pragma("unroll") for (int i = 0; i < 2; ++i)                      \
            _Pragma("unroll") for (int j = 0; j < 2; ++j)                      \
                acc[i][j] = __builtin_amdgcn_mfma_f32_32x32x16_bf16(           \
                    af[i], bfr[j], acc[i][j], 0, 0, 0);                        \
        }                                                                      \
        __syncthreads();                                                       \
    }

// ---------------------------------------------------------------------------
// GEMM1: mid = gelu(xg @ w1b[e] + b1[e]), bf16 out.
// ---------------------------------------------------------------------------
__global__ __launch_bounds__(256, 4)
void moe_gemm1(const bf16* __restrict__ Abase, const bf16* __restrict__ Bbase,
               const float* __restrict__ bias, bf16* __restrict__ Out,
               const int* __restrict__ tiles, const int* __restrict__ offsets)
{
    int info = tiles[blockIdx.x];
    if (info < 0) return;
    int e = info >> 24, row0 = info & 0xffffff;
    int valid = offsets[e + 1] - row0; if (valid > 128) valid = 128;
    int n0 = blockIdx.y * 128;

    const bf16* A = Abase + (size_t)row0 * DDIM;
    const bf16* B = Bbase + (size_t)e * HDIM * DDIM + (size_t)n0 * DDIM;
    const float* bvec = bias + (size_t)e * HDIM + n0;

    __shared__ __align__(16) bf16 As[128 * 64];
    __shared__ __align__(16) bf16 Bs[128 * 64];

    GEMM_CORE(DDIM)

    // epilogue: C/D col = lane&31, row = (reg&3)+8*(reg>>2)+4*(lane>>5)
#pragma unroll
    for (int i = 0; i < 2; ++i) {
#pragma unroll
        for (int j = 0; j < 2; ++j) {
            int lcol = wc * 64 + j * 32 + m32;
            float bj = bvec[lcol];
#pragma unroll
            for (int r = 0; r < 16; ++r) {
                int lrow = wr * 64 + i * 32 + (r & 3) + 8 * (r >> 2) + 4 * khalf;
                if (lrow >= valid) continue;
                float v = acc[i][j][r] + bj;
                Out[(size_t)(row0 + lrow) * HDIM + n0 + lcol] = (bf16)fast_gelu(v);
            }
        }
    }
}

// ---------------------------------------------------------------------------
// GEMM2: out[token] += w * (mid @ w2b[e] + b2[e])  -- fused combine via
// fp32 HW atomics (out zero-initialized by a memset node).
// ---------------------------------------------------------------------------
__global__ __launch_bounds__(256, 4)
void moe_gemm2(const bf16* __restrict__ Abase, const bf16* __restrict__ Bbase,
               const float* __restrict__ bias, float* __restrict__ out,
               const int* __restrict__ tiles, const int* __restrict__ offsets,
               const int* __restrict__ token_of, const float* __restrict__ wtab)
{
    int info = tiles[blockIdx.x];
    if (info < 0) return;
    int e = info >> 24, row0 = info & 0xffffff;
    int valid = offsets[e + 1] - row0; if (valid > 128) valid = 128;
    int n0 = blockIdx.y * 128;

    const bf16* A = Abase + (size_t)row0 * HDIM;
    const bf16* B = Bbase + (size_t)e * DDIM * HDIM + (size_t)n0 * HDIM;
    const float* bvec = bias + (size_t)e * DDIM + n0;

    __shared__ __align__(16) bf16 As[128 * 64];
    __shared__ __align__(16) bf16 Bs[128 * 64];

    GEMM_CORE(HDIM)

    // stage row -> (token, weight) map into (now-free) As LDS
    int*   tokS = (int*)As;
    float* wgtS = (float*)As + 128;
    if (tid < valid) {
        int s = row0 + tid - offsets[e];
        tokS[tid] = token_of[e * CAP + s];
        wgtS[tid] = wtab[e * CAP + s];
    }
    __syncthreads();

#pragma unroll
    for (int i = 0; i < 2; ++i) {
#pragma unroll
        for (int j = 0; j < 2; ++j) {
            int lcol = wc * 64 + j * 32 + m32;
            float bj = bvec[lcol];
#pragma unroll
            for (int r = 0; r < 16; ++r) {
                int lrow = wr * 64 + i * 32 + (r & 3) + 8 * (r >> 2) + 4 * khalf;
                if (lrow >= valid) continue;
                float v = acc[i][j][r] + bj;
                unsafeAtomicAdd(out + (size_t)tokS[lrow] * DDIM + n0 + lcol,
                                wgtS[lrow] * v);
            }
        }
    }
}

// ---------------------------------------------------------------------------
extern "C" void kernel_launch(void* const* d_in, const int* in_sizes, int n_in,
                              void* d_out, int out_size, void* d_ws, size_t ws_size,
                              hipStream_t stream)
{
    (void)in_sizes; (void)n_in; (void)out_size; (void)ws_size;
    const float* x  = (const float*)d_in[0];
    const float* gw = (const float*)d_in[1];
    const float* gb = (const float*)d_in[2];
    const float* w1 = (const float*)d_in[3];
    const float* b1 = (const float*)d_in[4];
    const float* w2 = (const float*)d_in[5];
    const float* b2 = (const float*)d_in[6];
    float* out    = (float*)d_out;
    float* logits = out + (size_t)T_TOKENS * DDIM;

    char* ws = (char*)d_ws;
    const size_t MB = 1024 * 1024;
    int*   counts   = (int*)(ws + 0);
    int*   offsets  = (int*)(ws + 256);
    int*   tiles    = (int*)(ws + 512);                  // 136 ints
    int*   selpack  = (int*)(ws + 4096);                 // 32 KB
    int*   token_of = (int*)(ws + 4096 + 64 * 1024);     // 256 KB
    float* wtab     = (float*)(ws + 4096 + 320 * 1024);  // 256 KB
    bf16*  xg  = (bf16*)(ws + 1 * MB);    // 32 MB
    bf16*  w1b = (bf16*)(ws + 33 * MB);   // [E][H][D] 64 MB
    bf16*  w2b = (bf16*)(ws + 97 * MB);   // [E][D][H] 64 MB
    bf16*  mid = (bf16*)(ws + 161 * MB);  // 128 MB

    hipMemsetAsync(counts, 0, 32, stream);
    hipMemsetAsync(out, 0, (size_t)T_TOKENS * DDIM * sizeof(float), stream);

    router_kernel<<<T_TOKENS / 4, 256, 0, stream>>>(x, gw, gb, logits, counts,
                                                    token_of, wtab, selpack);
    offsets_kernel<<<1, 64, 0, stream>>>(counts, offsets, tiles);
    gather_kernel<<<2 * T_TOKENS / 4, 256, 0, stream>>>(x, offsets, token_of, xg);
    // w1: [E][1024][4096] -> w1b [E][4096][1024]
    transpose_cvt_kernel<<<dim3(HDIM / 64, DDIM / 64, NEXP), 256, 0, stream>>>(
        w1, w1b, DDIM, HDIM);
    // w2: [E][4096][1024] -> w2b [E][1024][4096]
    transpose_cvt_kernel<<<dim3(DDIM / 64, HDIM / 64, NEXP), 256, 0, stream>>>(
        w2, w2b, HDIM, DDIM);
    moe_gemm1<<<dim3(MAXTILES, HDIM / 128), 256, 0, stream>>>(
        xg, w1b, b1, mid, tiles, offsets);
    moe_gemm2<<<dim3(MAXTILES, DDIM / 128), 256, 0, stream>>>(
        mid, w2b, b2, out, tiles, offsets, token_of, wtab);
}

// Round 5
// 961.785 us; speedup vs baseline: 1.0905x; 1.0905x over previous
//
#include <hip/hip_runtime.h>
#include <hip/hip_bf16.h>
#include <math.h>

#define T_TOKENS 8192
#define DDIM 1024
#define HDIM 4096
#define NEXP 8
#define CAP 8192      // max tokens per expert
#define MAXTILES 136  // sum_e ceil(cnt_e/128) <= 128 + 7; 136 % 8 == 0 (XCD math)

typedef __bf16 bf16;
typedef __bf16 bf16x4 __attribute__((ext_vector_type(4)));
typedef __bf16 bf16x8 __attribute__((ext_vector_type(8)));
typedef float  floatx4 __attribute__((ext_vector_type(4)));

// async global->LDS, 16 bytes per lane; LDS dest = wave-uniform base + lane*16.
__device__ static inline void async_load16(const void* g, void* l)
{
    __builtin_amdgcn_global_load_lds(
        (const __attribute__((address_space(1))) void*)g,
        (__attribute__((address_space(3))) void*)l, 16, 0, 0);
}

// ---------------------------------------------------------------------------
// Kernel 1: router. 4 waves/block, one token per wave. fp32 logits (exact;
// selection matches jax.lax.top_k incl. lowest-index tie-break).
// ---------------------------------------------------------------------------
__global__ void router_kernel(const float* __restrict__ x,
                              const float* __restrict__ gw,
                              const float* __restrict__ gbias,
                              float* __restrict__ logits_out,
                              int* counts, int* token_of,
                              int* selpack, int* slots, float* wts)
{
    int t = blockIdx.x * 4 + (threadIdx.x >> 6);
    int l = threadIdx.x & 63;
    const float4* xr = (const float4*)(x + (size_t)t * DDIM);

    float p[NEXP];
#pragma unroll
    for (int e = 0; e < NEXP; ++e) p[e] = 0.f;

#pragma unroll
    for (int it = 0; it < 4; ++it) {
        int d4 = it * 64 + l;
        float4 v = xr[d4];
        float vv[4] = {v.x, v.y, v.z, v.w};
#pragma unroll
        for (int j = 0; j < 4; ++j) {
            const float4* g4 = (const float4*)(gw + (size_t)(d4 * 4 + j) * NEXP);
            float4 ga = g4[0], gb4 = g4[1];
            p[0] += vv[j] * ga.x;  p[1] += vv[j] * ga.y;
            p[2] += vv[j] * ga.z;  p[3] += vv[j] * ga.w;
            p[4] += vv[j] * gb4.x; p[5] += vv[j] * gb4.y;
            p[6] += vv[j] * gb4.z; p[7] += vv[j] * gb4.w;
        }
    }
#pragma unroll
    for (int e = 0; e < NEXP; ++e) {
#pragma unroll
        for (int off = 32; off; off >>= 1) p[e] += __shfl_xor(p[e], off);
        p[e] += gbias[e];
    }
    if (l < NEXP) logits_out[(size_t)t * NEXP + l] = p[l];

    if (l == 0) {
        int e0 = 0;
#pragma unroll
        for (int e = 1; e < NEXP; ++e) if (p[e] > p[e0]) e0 = e;
        int e1 = -1;
#pragma unroll
        for (int e = 0; e < NEXP; ++e) {
            if (e == e0) continue;
            if (e1 < 0 || p[e] > p[e1]) e1 = e;
        }
        float w0 = 1.f / (1.f + expf(p[e1] - p[e0]));
        float w1 = 1.f / (1.f + expf(p[e0] - p[e1]));
        int s0 = atomicAdd(&counts[e0], 1);
        int s1 = atomicAdd(&counts[e1], 1);
        token_of[e0 * CAP + s0] = t;
        token_of[e1 * CAP + s1] = t;
        selpack[t] = e0 | (e1 << 8);
        slots[2 * t]     = s0;
        slots[2 * t + 1] = s1;
        wts[2 * t]     = w0;
        wts[2 * t + 1] = w1;
    }
}

// ---------------------------------------------------------------------------
// Kernel 2: offsets + XCD-transposed 128-row tile list.
// tiles[p] for p = c + 8*k carries ordered-tile index c*per + k, so a
// contiguous (≈ one expert) run of tiles lands on one XCD (linear%8 == p%8
// since grid.x == 136 ≡ 0 mod 8) -> each XCD's L2 sees ~one expert's B.
// [R4 verified: GEMM2 FETCH 600 -> 293 MB]
// ---------------------------------------------------------------------------
__global__ void offsets_kernel(const int* __restrict__ counts,
                               int* __restrict__ offsets,
                               int* __restrict__ tiles)
{
    if (threadIdx.x == 0) {
        int tmp[MAXTILES];
        int a = 0, nt = 0;
        for (int e = 0; e < NEXP; ++e) {
            offsets[e] = a;
            for (int r = 0; r < counts[e]; r += 128)
                tmp[nt++] = (e << 24) | (a + r);
            a += counts[e];
        }
        offsets[NEXP] = a;   // == 2*T_TOKENS
        int per = (nt + 7) >> 3;
        for (int p = 0; p < MAXTILES; ++p) {
            int c = p & 7, k = p >> 3;
            int src = c * per + k;
            tiles[p] = (k < per && src < nt) ? tmp[src] : -1;
        }
    }
}

// ---------------------------------------------------------------------------
// Kernel 3: gather over compact rows. 4 waves/block, one row per wave.
// ---------------------------------------------------------------------------
__global__ void gather_kernel(const float* __restrict__ x,
                              const int* __restrict__ offsets,
                              const int* __restrict__ token_of,
                              bf16* __restrict__ xg)
{
    int row = blockIdx.x * 4 + (threadIdx.x >> 6);
    int l = threadIdx.x & 63;
    int e = 0;
#pragma unroll
    for (int i = 1; i < NEXP; ++i) e += (row >= offsets[i]);
    int t = token_of[e * CAP + (row - offsets[e])];
    const float4* src = (const float4*)(x + (size_t)t * DDIM);
    bf16x4* dst = (bf16x4*)(xg + (size_t)row * DDIM);
#pragma unroll
    for (int it = 0; it < 4; ++it) {
        float4 v = src[it * 64 + l];
        bf16x4 b;
        b[0] = (bf16)v.x; b[1] = (bf16)v.y; b[2] = (bf16)v.z; b[3] = (bf16)v.w;
        dst[it * 64 + l] = b;
    }
}

// ---------------------------------------------------------------------------
// Kernel 4: both weight transposes in ONE launch (fp32 [E][R][C] -> bf16
// [E][C][R]).  blocks 0..8191: w1 (R=1024,C=4096); 8192..16383: w2 (swap).
// 64x64 tile, 256 threads, 16 B/lane both directions.
// ---------------------------------------------------------------------------
__global__ void transpose_cvt_kernel(const float* __restrict__ w1,
                                     const float* __restrict__ w2,
                                     bf16* __restrict__ w1b,
                                     bf16* __restrict__ w2b)
{
    __shared__ bf16 tile[64][68];
    int b = blockIdx.x;
    int R, C, e, tr, tc;
    const float* src;
    bf16* dst;
    if (b < 8192) {
        R = DDIM; C = HDIM;
        e = b >> 10; int tt = b & 1023;        // 1024 tiles: 64(c) x 16(r)
        tc = tt & 63; tr = tt >> 6;
        src = w1 + (size_t)e * R * C; dst = w1b + (size_t)e * R * C;
    } else {
        b -= 8192;
        R = HDIM; C = DDIM;
        e = b >> 10; int tt = b & 1023;        // 1024 tiles: 16(c) x 64(r)
        tc = tt & 15; tr = tt >> 4;
        src = w2 + (size_t)e * R * C; dst = w2b + (size_t)e * R * C;
    }
    int r0 = tr * 64, c0 = tc * 64;
    int t = threadIdx.x;
    int lr = t >> 4, c4 = t & 15;
#pragma unroll
    for (int it = 0; it < 4; ++it) {
        int r = lr + it * 16;
        float4 v = *(const float4*)(src + (size_t)(r0 + r) * C + c0 + c4 * 4);
        bf16x4 bb;
        bb[0] = (bf16)v.x; bb[1] = (bf16)v.y; bb[2] = (bf16)v.z; bb[3] = (bf16)v.w;
        *(bf16x4*)(&tile[r][c4 * 4]) = bb;
    }
    __syncthreads();
    int oc = t >> 3, rseg = (t & 7) * 8;
#pragma unroll
    for (int it = 0; it < 2; ++it) {
        int c = oc + it * 32;
        bf16x8 v;
#pragma unroll
        for (int j = 0; j < 8; ++j) v[j] = tile[rseg + j][c];
        *(bf16x8*)(dst + (size_t)(c0 + c) * R + r0 + rseg) = v;
    }
}

// ---------------------------------------------------------------------------
// Stage 128x64 bf16 tile -> unpadded LDS via global_load_lds, XOR chunk
// swizzle on the global side (phys chunk p holds logical p ^ (row&7)).
// ---------------------------------------------------------------------------
template<int KTOT>
__device__ static inline void stage_tile(const bf16* __restrict__ gbase,
                                         bf16* lds, int wave, int lane, int valid)
{
#pragma unroll
    for (int it = 0; it < 4; ++it) {
        int rbase = wave * 32 + it * 8;          // wave-uniform
        int rloc  = rbase + (lane >> 3);
        int grow  = rloc < valid ? rloc : (valid - 1);
        int chunk = (lane & 7) ^ (rloc & 7);
        const bf16* g = gbase + (size_t)grow * KTOT + chunk * 8;
        async_load16(g, lds + rbase * 64);
    }
}

__device__ static inline float fast_gelu(float v)
{
    float z = v * (2.302236479f + 0.1029451170f * v * v);
    float ex = __builtin_amdgcn_exp2f(z);
    return v * ex * __builtin_amdgcn_rcpf(ex + 1.f);
}

// ---------------------------------------------------------------------------
// MFMA GEMM over XCD-swizzled tile list. 16x16x32 core (r3-verified: 0 LDS
// conflicts, best measured rate). A: [rows,KTOT] bf16. B: [E][NTOT][KTOT].
// 128x128 tile, BK=64, 4 waves x (64x64 via 4x4 mfma_16x16x32).
// ---------------------------------------------------------------------------
template<int KTOT, int NTOT, bool DOGELU, typename OutT>
__global__ __launch_bounds__(256, 4)
void moe_gemm(const bf16* __restrict__ Abase, const bf16* __restrict__ Bbase,
              const float* __restrict__ bias, OutT* __restrict__ Out,
              const int* __restrict__ tiles, const int* __restrict__ offsets)
{
    int info = tiles[blockIdx.x];
    if (info < 0) return;
    int e = info >> 24, row0 = info & 0xffffff;
    int valid = offsets[e + 1] - row0; if (valid > 128) valid = 128;
    int n0 = blockIdx.y * 128;

    const bf16* A = Abase + (size_t)row0 * KTOT;
    const bf16* B = Bbase + (size_t)e * NTOT * KTOT + (size_t)n0 * KTOT;
    const float* bvec = bias + (size_t)e * NTOT + n0;

    __shared__ __align__(16) bf16 As[128 * 64];
    __shared__ __align__(16) bf16 Bs[128 * 64];

    int tid = threadIdx.x;
    int lane = tid & 63, wave = tid >> 6;
    int wr = wave >> 1, wc = wave & 1;
    int m16 = lane & 15, quad = lane >> 4;
    int swz = m16 & 7;

    floatx4 acc[4][4];
#pragma unroll
    for (int i = 0; i < 4; ++i)
#pragma unroll
        for (int j = 0; j < 4; ++j)
#pragma unroll
            for (int r = 0; r < 4; ++r) acc[i][j][r] = 0.f;

    for (int k0 = 0; k0 < KTOT; k0 += 64) {
        stage_tile<KTOT>(A + k0, As, wave, lane, valid);
        stage_tile<KTOT>(B + k0, Bs, wave, lane, 128);
        __syncthreads();
#pragma unroll
        for (int ks = 0; ks < 64; ks += 32) {
            int cbase = (ks >> 3) + quad;
            int pchunk = (cbase ^ swz) * 8;
            bf16x8 af[4], bfr[4];
#pragma unroll
            for (int i = 0; i < 4; ++i)
                af[i] = *(const bf16x8*)(&As[(wr * 64 + i * 16 + m16) * 64 + pchunk]);
#pragma unroll
            for (int j = 0; j < 4; ++j)
                bfr[j] = *(const bf16x8*)(&Bs[(wc * 64 + j * 16 + m16) * 64 + pchunk]);
#pragma unroll
            for (int i = 0; i < 4; ++i)
#pragma unroll
                for (int j = 0; j < 4; ++j)
                    acc[i][j] = __builtin_amdgcn_mfma_f32_16x16x32_bf16(
                        af[i], bfr[j], acc[i][j], 0, 0, 0);
        }
        __syncthreads();
    }

    // epilogue: C/D layout col = lane&15, row = quad*4 + reg  [m89-verified]
#pragma unroll
    for (int i = 0; i < 4; ++i) {
#pragma unroll
        for (int r = 0; r < 4; ++r) {
            int lrow = wr * 64 + i * 16 + quad * 4 + r;
            if (lrow >= valid) continue;
            size_t orow = (size_t)(row0 + lrow) * NTOT + n0;
#pragma unroll
            for (int j = 0; j < 4; ++j) {
                int lcol = wc * 64 + j * 16 + m16;
                float v = acc[i][j][r] + bvec[lcol];
                if (DOGELU) v = fast_gelu(v);
                Out[orow + lcol] = (OutT)v;
            }
        }
    }
}

// ---------------------------------------------------------------------------
// Kernel 7: combine. out[t] = w0*y[pos0] + w1*y[pos1].
// ---------------------------------------------------------------------------
__global__ void combine_kernel(const float* __restrict__ y,
                               const int* __restrict__ offsets,
                               const int* __restrict__ selpack,
                               const int* __restrict__ slots,
                               const float* __restrict__ wts,
                               float* __restrict__ out)
{
    int t = blockIdx.x;
    int sp = selpack[t];
    int e0 = sp & 0xff, e1 = (sp >> 8) & 0xff;
    int p0 = offsets[e0] + slots[2 * t];
    int p1 = offsets[e1] + slots[2 * t + 1];
    float w0 = wts[2 * t], w1 = wts[2 * t + 1];
    const float4* y0 = (const float4*)(y + (size_t)p0 * DDIM);
    const float4* y1 = (const float4*)(y + (size_t)p1 * DDIM);
    float4* o = (float4*)(out + (size_t)t * DDIM);
    int tid = threadIdx.x;
    float4 a = y0[tid], b = y1[tid];
    float4 rr;
    rr.x = w0 * a.x + w1 * b.x;
    rr.y = w0 * a.y + w1 * b.y;
    rr.z = w0 * a.z + w1 * b.z;
    rr.w = w0 * a.w + w1 * b.w;
    o[tid] = rr;
}

// ---------------------------------------------------------------------------
extern "C" void kernel_launch(void* const* d_in, const int* in_sizes, int n_in,
                              void* d_out, int out_size, void* d_ws, size_t ws_size,
                              hipStream_t stream)
{
    (void)in_sizes; (void)n_in; (void)out_size; (void)ws_size;
    const float* x  = (const float*)d_in[0];
    const float* gw = (const float*)d_in[1];
    const float* gb = (const float*)d_in[2];
    const float* w1 = (const float*)d_in[3];
    const float* b1 = (const float*)d_in[4];
    const float* w2 = (const float*)d_in[5];
    const float* b2 = (const float*)d_in[6];
    float* out    = (float*)d_out;
    float* logits = out + (size_t)T_TOKENS * DDIM;

    char* ws = (char*)d_ws;
    const size_t MB = 1024 * 1024;
    int*   counts   = (int*)(ws + 0);
    int*   offsets  = (int*)(ws + 256);
    int*   tiles    = (int*)(ws + 512);                  // 136 ints
    int*   selpack  = (int*)(ws + 4096);                 // 32 KB
    int*   slots    = (int*)(ws + 4096 + 32 * 1024);     // 64 KB
    float* wts      = (float*)(ws + 4096 + 96 * 1024);   // 64 KB
    int*   token_of = (int*)(ws + 4096 + 160 * 1024);    // 256 KB
    bf16*  xg  = (bf16*)(ws + 1 * MB);    // 32 MB
    bf16*  w1b = (bf16*)(ws + 33 * MB);   // [E][H][D] 64 MB
    bf16*  w2b = (bf16*)(ws + 97 * MB);   // [E][D][H] 64 MB
    bf16*  mid = (bf16*)(ws + 161 * MB);  // 128 MB
    float* y   = (float*)(ws + 289 * MB); // 64 MB

    hipMemsetAsync(counts, 0, 32, stream);

    router_kernel<<<T_TOKENS / 4, 256, 0, stream>>>(x, gw, gb, logits, counts,
                                                    token_of, selpack, slots, wts);
    offsets_kernel<<<1, 64, 0, stream>>>(counts, offsets, tiles);
    gather_kernel<<<2 * T_TOKENS / 4, 256, 0, stream>>>(x, offsets, token_of, xg);
    transpose_cvt_kernel<<<16384, 256, 0, stream>>>(w1, w2, w1b, w2b);
    // GEMM1: mid = gelu(xg @ w1b[e] + b1[e])
    moe_gemm<DDIM, HDIM, true, bf16><<<dim3(MAXTILES, HDIM / 128), 256, 0, stream>>>(
        xg, w1b, b1, mid, tiles, offsets);
    // GEMM2: y = mid @ w2b[e] + b2[e]
    moe_gemm<HDIM, DDIM, false, float><<<dim3(MAXTILES, DDIM / 128), 256, 0, stream>>>(
        mid, w2b, b2, y, tiles, offsets);
    combine_kernel<<<T_TOKENS, 256, 0, stream>>>(y, offsets, selpack, slots, wts, out);
}